// Round 5
// baseline (2894372.266 us; speedup 1.0000x reference)
//
#include <hip/hip_runtime.h>

typedef __attribute__((ext_vector_type(8))) short short8;
typedef __attribute__((ext_vector_type(4))) short short4v;
typedef __attribute__((ext_vector_type(4))) float f32x4;
typedef __attribute__((ext_vector_type(4))) int int4v;
typedef unsigned long long ull;

constexpr int H    = 516;    // hidden
constexpr int GP   = 2080;   // padded gate cols (65*32), permuted chat = 4*u+g
constexpr int KH   = 544;    // padded hidden K (17*32)
constexpr int KE   = 256;    // embedding dim
constexpr int NB   = 65;     // recurrence blocks (8 units each -> 520 padded units)
constexpr int SB   = 32;     // batch
constexpr int SEQ  = 64;
constexpr int MROW = 2048;   // SEQ*SB
constexpr int V    = 32000;
constexpr int NBN  = 250;    // V/128
constexpr int HSROW = 552;   // padded LDS row stride (shorts) -> conflict-free b128
// tagged h exchange: per 4B data dword, a 4B gen dword. Row = 272 pairs = 2176B.
// layout: [parity][layer][batch32][272 pairs]; parity stride = 2*32*2176 = 139264 B.

__device__ __forceinline__ float bf2f(short s) {
  unsigned u = ((unsigned)(unsigned short)s) << 16;
  float f; __builtin_memcpy(&f, &u, 4); return f;
}
__device__ __forceinline__ short f2bf(float f) {
  unsigned u; __builtin_memcpy(&u, &f, 4);
  u += 0x7fffu + ((u >> 16) & 1u);
  return (short)(u >> 16);
}
__device__ __forceinline__ float sigm(float x){ return 1.f/(1.f+__expf(-x)); }
__device__ __forceinline__ float tanh_(float x){ float e=__expf(-2.f*x); return (1.f-e)/(1.f+e); }

// ---------------- pack kernels ----------------
__global__ void k_pack_gates(const float* __restrict__ W1, const float* __restrict__ W2,
                             short* __restrict__ dst, int ksteps) {
  int gid = blockIdx.x * 256 + threadIdx.x;
  int total = NB * 2 * ksteps * 64;
  if (gid >= total) return;
  int lane = gid & 63;
  int rest = gid >> 6;
  int ks = rest % ksteps; rest /= ksteps;
  int nt = rest & 1; int bid = rest >> 1;
  int chat = bid * 32 + nt * 16 + (lane & 15);
  int u = chat >> 2, g = chat & 3;
  int kb = ks * 32 + (lane >> 4) * 8;
  short8 v;
#pragma unroll
  for (int j = 0; j < 8; ++j) {
    int k = kb + j;
    const float* src = W1; int kk = k;
    if (k >= KH) { src = W2; kk = k - KH; }
    float f = 0.f;
    if (u < H && kk < H) f = src[(size_t)(g * H + u) * H + kk];
    v[j] = f2bf(f);
  }
  *(short8*)(dst + (size_t)gid * 8) = v;
}

__global__ void k_pack_wout(const float* __restrict__ Wout, short* __restrict__ dst) {
  int gid = blockIdx.x * 256 + threadIdx.x;          // group of 8
  if (gid >= V * (KH / 8)) return;
  int row = gid / (KH / 8);
  int kb = (gid % (KH / 8)) * 8;
  short8 v;
#pragma unroll
  for (int j = 0; j < 8; ++j) {
    int k = kb + j;
    v[j] = f2bf(k < H ? Wout[(size_t)row * H + k] : 0.f);
  }
  *(short8*)(dst + (size_t)gid * 8) = v;
}

__global__ void k_pack_wih(const float* __restrict__ Wih0, short* __restrict__ dst) {
  int gid = blockIdx.x * 256 + threadIdx.x;          // group of 8
  if (gid >= GP * (KE / 8)) return;
  int chat = gid / (KE / 8);
  int kb = (gid % (KE / 8)) * 8;
  int u = chat >> 2, g = chat & 3;
  short8 v;
#pragma unroll
  for (int j = 0; j < 8; ++j)
    v[j] = f2bf(u < H ? Wih0[(size_t)(g * H + u) * KE + kb + j] : 0.f);
  *(short8*)(dst + (size_t)gid * 8) = v;
}

__global__ void k_pack_bias(const float* ebih0, const float* ebhh0, const float* ebih1, const float* ebhh1,
                            const float* dbih0, const float* dbhh0, const float* dbih1, const float* dbhh1,
                            float* b0e, float* b1e, float* b0d, float* b1d) {
  int chat = blockIdx.x * 256 + threadIdx.x;
  if (chat >= GP) return;
  int u = chat >> 2, g = chat & 3, n = g * H + u;
  bool ok = (u < H);
  b0e[chat] = ok ? ebih0[n] + ebhh0[n] : 0.f;
  b1e[chat] = ok ? ebih1[n] + ebhh1[n] : 0.f;
  b0d[chat] = ok ? dbih0[n] + dbhh0[n] : 0.f;
  b1d[chat] = ok ? dbih1[n] + dbhh1[n] : 0.f;
}

// ---------------- batched input projection (X0 stored bf16) ----------------
__global__ void __launch_bounds__(256) k_embproj(const short* __restrict__ WihP,
                                                 const float* __restrict__ emb,
                                                 const int* __restrict__ toks,
                                                 const float* __restrict__ b0P,
                                                 short* __restrict__ X0P) {
  int tid = threadIdx.x, w = tid >> 6, lane = tid & 63, q = lane >> 4, col = lane & 15;
  int mt = blockIdx.x;                 // 0..129
  int ntile = blockIdx.y * 4 + w;      // 0..127
  int tb = ntile * 16 + col;
  int tok = toks[tb];
  const short* Ap = WihP + (size_t)(mt * 16 + col) * KE + q * 8;
  const float* Bp = emb + (size_t)tok * KE + q * 8;
  f32x4 acc = {0.f, 0.f, 0.f, 0.f};
#pragma unroll
  for (int ks = 0; ks < 8; ++ks) {
    short8 a = *(const short8*)(Ap + ks * 32);
    const f32x4* b4 = (const f32x4*)(Bp + ks * 32);
    f32x4 b0v = b4[0], b1v = b4[1];
    short8 bb;
    bb[0]=f2bf(b0v[0]); bb[1]=f2bf(b0v[1]); bb[2]=f2bf(b0v[2]); bb[3]=f2bf(b0v[3]);
    bb[4]=f2bf(b1v[0]); bb[5]=f2bf(b1v[1]); bb[6]=f2bf(b1v[2]); bb[7]=f2bf(b1v[3]);
    acc = __builtin_amdgcn_mfma_f32_16x16x32_bf16(a, bb, acc, 0, 0, 0);
  }
  int chat0 = mt * 16 + q * 4;
  f32x4 bias = *(const f32x4*)(b0P + chat0);
  int t = tb >> 5, b = tb & 31;
  short* dst = X0P + ((size_t)t * GP) * 32 + b;
#pragma unroll
  for (int r = 0; r < 4; ++r)
    dst[(size_t)(chat0 + r) * 32] = f2bf(acc[r] + bias[r]);
}

// ---------------- cooperative recurrence ----------------
// Barrier fused into data: gen-tagged [data4|gen4] pairs at the coherence point.
// Consumers burst-load optimistically; retry (bounded) until all gens >= iter.
struct RecArgs {
  const short *WAe, *WBe, *WAd, *WBd;
  const short *X0e, *X0d;
  const float *b1e, *b1d;
  char *hst;                // tagged exchange: 2 parity x 139264 B
  short *H1P;
};

__global__ void __launch_bounds__(256, 1) k_recur(RecArgs A) {
  const int tid = threadIdx.x, lane = tid & 63, w = tid >> 6;
  const int q = lane >> 4, col = lane & 15;
  const int mt = w >> 1, nt = w & 1;
  const int bid = blockIdx.x;
  const int chat_l = nt * 16 + col, chat = bid * 32 + chat_l;
  const int am = mt * 16 + col;               // A-fragment row (batch index)
  __shared__ __align__(16) short hs[2][32][HSROW];   // staged h0,h1
  __shared__ float c0[32][8], c1[32][8];
  __shared__ float gbuf0[32][33], gbuf1[32][33];
  const int tl = tid & 127, cb = tl >> 2, up = tl & 3;
  if (tid < 128) { c0[cb][up * 2] = 0.f; c0[cb][up * 2 + 1] = 0.f; }
  else           { c1[cb][up * 2] = 0.f; c1[cb][up * 2 + 1] = 0.f; }

  // staging chunk map: chunk c = tid + 256*j covers data shorts [c*8, c*8+8)
  short* hsflat = &hs[0][0][0];
  int loff[17], goff[17];
#pragma unroll
  for (int j = 0; j < 17; ++j) {
    int c = tid + 256 * j;
    int L = (c >= 2176) ? 1 : 0;
    int cc = c - L * 2176;
    int row = cc / 68, kc = cc - row * 68;
    loff[j] = (L * 32 + row) * HSROW + kc * 8;          // shorts (LDS)
    goff[j] = (L * 32 + row) * 2176 + kc * 32;          // bytes (tagged global)
  }

  const float b1ev = A.b1e[chat];
  const float b1dv = A.b1d[chat];
  short4v xr_n = *(const short4v*)(A.X0e + ((size_t)0 * GP + chat) * 32 + mt * 16 + q * 4);

  for (int i = 0; i <= 128; ++i) {
    const int wp = i & 1, rp = wp ^ 1;
    const short4v xr = xr_n;
    if (i + 1 < 128) {    // prefetch X0 for next iter (overlaps the retry spin)
      const int in = i + 1;
      const short* X0n = (in >> 6) ? A.X0d : A.X0e;
      xr_n = *(const short4v*)(X0n + ((size_t)(in & 63) * GP + chat) * 32 + mt * 16 + q * 4);
    }

    // ---- stage h[rp] (both layers) with fused readiness check ----
    {
      const char* gbase = A.hst + (size_t)rp * 139264;
      const char* ga[17];
#pragma unroll
      for (int j = 0; j < 17; ++j) ga[j] = gbase + goff[j];
      const unsigned tgt = (unsigned)i;
      int4v ta[17], tb[17];
      int spin = 0;
      while (true) {
#pragma unroll
        for (int j = 0; j < 17; ++j) {
          asm volatile("global_load_dwordx4 %0, %1, off sc0 sc1"
                       : "=v"(ta[j]) : "v"(ga[j]) : "memory");
          asm volatile("global_load_dwordx4 %0, %1, off offset:16 sc0 sc1"
                       : "=v"(tb[j]) : "v"(ga[j]) : "memory");
        }
        asm volatile("s_waitcnt vmcnt(0)" ::: "memory");
        bool ok = true;
#pragma unroll
        for (int j = 0; j < 17; ++j)
          ok = ok && ((unsigned)ta[j].y >= tgt) && ((unsigned)ta[j].w >= tgt) &&
                     ((unsigned)tb[j].y >= tgt) && ((unsigned)tb[j].w >= tgt);
        if (__all(ok)) break;
        if (++spin > 20000) break;   // failsafe: never hang the device
      }
#pragma unroll
      for (int j = 0; j < 17; ++j) {
        union { int4v i4; short s[8]; } ua, ub;
        ua.i4 = ta[j]; ub.i4 = tb[j];
        short8 d;
        d[0] = ua.s[0]; d[1] = ua.s[1]; d[2] = ua.s[4]; d[3] = ua.s[5];
        d[4] = ub.s[0]; d[5] = ub.s[1]; d[6] = ub.s[4]; d[7] = ub.s[5];
        *(short8*)(hsflat + loff[j]) = d;
      }
    }
    __syncthreads();

    // ---- both layers' gate GEMMs from LDS ----
    const int ph0 = (i < 128) ? (i >> 6) : 1;
    const int i1 = i - 1;
    const int ph1 = (i >= 1) ? (i1 >> 6) : 0;
    const short* WA = (ph0 ? A.WAd : A.WAe) + (size_t)bid * 17408 + (size_t)(nt * 17 * 64 + lane) * 8;
    const short* WB = (ph1 ? A.WBd : A.WBe) + (size_t)bid * 34816 + (size_t)(nt * 34 * 64 + lane) * 8;
    f32x4 acc0 = {0.f, 0.f, 0.f, 0.f}, acc1 = {0.f, 0.f, 0.f, 0.f};
#pragma unroll
    for (int ks = 0; ks < 17; ++ks) {
      short8 a0 = *(const short8*)&hs[0][am][ks * 32 + q * 8];
      short8 a1 = *(const short8*)&hs[1][am][ks * 32 + q * 8];
      short8 w0 = *(const short8*)(WA + ks * 512);
      short8 w1 = *(const short8*)(WB + ks * 512);
      short8 w2 = *(const short8*)(WB + (size_t)(17 + ks) * 512);
      acc0 = __builtin_amdgcn_mfma_f32_16x16x32_bf16(a0, w0, acc0, 0, 0, 0);
      acc1 = __builtin_amdgcn_mfma_f32_16x16x32_bf16(a0, w1, acc1, 0, 0, 0);
      acc1 = __builtin_amdgcn_mfma_f32_16x16x32_bf16(a1, w2, acc1, 0, 0, 0);
    }
    {
      float b1v = ph1 ? b1dv : b1ev;
#pragma unroll
      for (int r = 0; r < 4; ++r) {
        gbuf0[mt * 16 + q * 4 + r][chat_l] = acc0[r] + bf2f(xr[r]);
        gbuf1[mt * 16 + q * 4 + r][chat_l] = acc1[r] + b1v;
      }
    }
    __syncthreads();

    // ---- cell updates + tagged h stores ----
    if (tid < 128) {
      if (i < 128) {
        unsigned hv = 0;
#pragma unroll
        for (int s = 0; s < 2; ++s) {
          int base = up * 8 + s * 4;
          float gi = gbuf0[cb][base + 0], gf = gbuf0[cb][base + 1];
          float gg = gbuf0[cb][base + 2], go = gbuf0[cb][base + 3];
          float c = c0[cb][up * 2 + s];
          float cn = sigm(gf) * c + sigm(gi) * tanh_(gg);
          float hn = sigm(go) * tanh_(cn);
          c0[cb][up * 2 + s] = cn;
          hv |= ((unsigned)(unsigned short)f2bf(hn)) << (16 * s);
        }
        ull val = ((ull)(unsigned)(i + 1) << 32) | hv;
        __hip_atomic_store((ull*)(A.hst + (size_t)wp * 139264 + cb * 2176 + (bid * 4 + up) * 8),
                           val, __ATOMIC_RELAXED, __HIP_MEMORY_SCOPE_AGENT);
      }
    } else {
      if (i >= 1) {
        unsigned hv = 0;
#pragma unroll
        for (int s = 0; s < 2; ++s) {
          int base = up * 8 + s * 4;
          float gi = gbuf1[cb][base + 0], gf = gbuf1[cb][base + 1];
          float gg = gbuf1[cb][base + 2], go = gbuf1[cb][base + 3];
          float c = c1[cb][up * 2 + s];
          float cn = sigm(gf) * c + sigm(gi) * tanh_(gg);
          float hn = sigm(go) * tanh_(cn);
          c1[cb][up * 2 + s] = cn;
          hv |= ((unsigned)(unsigned short)f2bf(hn)) << (16 * s);
        }
        ull val = ((ull)(unsigned)(i + 1) << 32) | hv;
        __hip_atomic_store((ull*)(A.hst + (size_t)wp * 139264 + 69632 + cb * 2176 + (bid * 4 + up) * 8),
                           val, __ATOMIC_RELAXED, __HIP_MEMORY_SCOPE_AGENT);
        if (i1 >= 64)
          *((unsigned*)A.H1P + (size_t)((i1 - 64) * SB + cb) * 272 + bid * 4 + up) = hv;
      } else {
        // bootstrap: publish h1=0 with gen 1 so stage at i=1 can complete
        ull val = ((ull)1u << 32);
        __hip_atomic_store((ull*)(A.hst + (size_t)wp * 139264 + 69632 + cb * 2176 + (bid * 4 + up) * 8),
                           val, __ATOMIC_RELAXED, __HIP_MEMORY_SCOPE_AGENT);
      }
    }
    // no grid barrier: next stage's tagged retry IS the barrier
  }
}

// ---------------- projection GEMM + streamed sum-exp ----------------
__global__ void __launch_bounds__(256) k_project(const short* __restrict__ H1P,
                                                 const short* __restrict__ WoutP,
                                                 const float* __restrict__ bout,
                                                 float* __restrict__ partials) {
  int bM = blockIdx.x, bN = blockIdx.y;
  int tid = threadIdx.x, w = tid >> 6, lane = tid & 63, q = lane >> 4, col = lane & 15;
  int wm = w >> 1, wn = w & 1;
  __shared__ __align__(16) short As[128 * 32];
  __shared__ __align__(16) short Bs[128 * 32];
  __shared__ float sred[128][2];
  f32x4 acc[4][4];
#pragma unroll
  for (int mi = 0; mi < 4; ++mi)
#pragma unroll
    for (int ni = 0; ni < 4; ++ni) acc[mi][ni] = (f32x4){0.f, 0.f, 0.f, 0.f};

  for (int ks = 0; ks < 17; ++ks) {
#pragma unroll
    for (int i = 0; i < 2; ++i) {
      int chunk = tid * 2 + i;               // 0..511
      int row = chunk >> 2, ch = chunk & 3;
      ((short8*)As)[chunk] = *(const short8*)(H1P  + (size_t)(bM * 128 + row) * KH + ks * 32 + ch * 8);
      ((short8*)Bs)[chunk] = *(const short8*)(WoutP + (size_t)(bN * 128 + row) * KH + ks * 32 + ch * 8);
    }
    __syncthreads();
    short8 af[4], bf[4];
#pragma unroll
    for (int mi = 0; mi < 4; ++mi) af[mi] = *(const short8*)(As + (wm * 64 + mi * 16 + col) * 32 + q * 8);
#pragma unroll
    for (int ni = 0; ni < 4; ++ni) bf[ni] = *(const short8*)(Bs + (wn * 64 + ni * 16 + col) * 32 + q * 8);
#pragma unroll
    for (int mi = 0; mi < 4; ++mi)
#pragma unroll
      for (int ni = 0; ni < 4; ++ni)
        acc[mi][ni] = __builtin_amdgcn_mfma_f32_16x16x32_bf16(af[mi], bf[ni], acc[mi][ni], 0, 0, 0);
    __syncthreads();
  }
  float bias[4];
#pragma unroll
  for (int ni = 0; ni < 4; ++ni) bias[ni] = bout[bN * 128 + wn * 64 + ni * 16 + col];
#pragma unroll
  for (int mi = 0; mi < 4; ++mi) {
#pragma unroll
    for (int r = 0; r < 4; ++r) {
      float s = 0.f;
#pragma unroll
      for (int ni = 0; ni < 4; ++ni) s += __expf(acc[mi][ni][r] + bias[ni]);
      s += __shfl_xor(s, 1, 64); s += __shfl_xor(s, 2, 64);
      s += __shfl_xor(s, 4, 64); s += __shfl_xor(s, 8, 64);
      if (col == 0) sred[wm * 64 + mi * 16 + q * 4 + r][wn] = s;
    }
  }
  __syncthreads();
  if (tid < 128)
    partials[(size_t)(bM * 128 + tid) * NBN + bN] = sred[tid][0] + sred[tid][1];
}

// ---------------- finish: lse + target logit + loss ----------------
__global__ void __launch_bounds__(256) k_finish(const float* __restrict__ partials,
                                                const short* __restrict__ H1P,
                                                const float* __restrict__ Wout,
                                                const float* __restrict__ bout,
                                                const int* __restrict__ y,
                                                float* __restrict__ out) {
  int tid = threadIdx.x, w = tid >> 6, lane = tid & 63;
  int row = blockIdx.x * 4 + w;           // 0..2047 (t*32+b)
  float s = 0.f;
  for (int j = lane; j < NBN; j += 64) s += partials[(size_t)row * NBN + j];
#pragma unroll
  for (int off = 32; off > 0; off >>= 1) s += __shfl_down(s, off, 64);
  int tok = y[row + 32];                  // y[(t+1)*32 + b]
  float d = 0.f;
  for (int k = lane; k < H; k += 64)
    d += bf2f(H1P[(size_t)row * KH + k]) * Wout[(size_t)tok * H + k];
#pragma unroll
  for (int off = 32; off > 0; off >>= 1) d += __shfl_down(d, off, 64);
  __shared__ float bsum[4];
  if (lane == 0) bsum[w] = __logf(s) - (d + bout[tok]);
  __syncthreads();
  if (tid == 0) atomicAdd(out, (bsum[0] + bsum[1] + bsum[2] + bsum[3]) * (1.f / 32.f));
}

// ---------------- host ----------------
extern "C" void kernel_launch(void* const* d_in, const int* in_sizes, int n_in,
                              void* d_out, int out_size, void* d_ws, size_t ws_size,
                              hipStream_t stream) {
  const int*   x      = (const int*)d_in[0];
  const int*   y      = (const int*)d_in[1];
  const float* encemb = (const float*)d_in[2];
  const float* decemb = (const float*)d_in[3];
  const float* eWih0  = (const float*)d_in[4];
  const float* eWhh0  = (const float*)d_in[5];
  const float* ebih0  = (const float*)d_in[6];
  const float* ebhh0  = (const float*)d_in[7];
  const float* eWih1  = (const float*)d_in[8];
  const float* eWhh1  = (const float*)d_in[9];
  const float* ebih1  = (const float*)d_in[10];
  const float* ebhh1  = (const float*)d_in[11];
  const float* dWih0  = (const float*)d_in[12];
  const float* dWhh0  = (const float*)d_in[13];
  const float* dbih0  = (const float*)d_in[14];
  const float* dbhh0  = (const float*)d_in[15];
  const float* dWih1  = (const float*)d_in[16];
  const float* dWhh1  = (const float*)d_in[17];
  const float* dbih1  = (const float*)d_in[18];
  const float* dbhh1  = (const float*)d_in[19];
  const float* Wout   = (const float*)d_in[20];
  const float* bout   = (const float*)d_in[21];
  float* out = (float*)d_out;

  char* wsb = (char*)d_ws;
  size_t off = 0;
  auto alloc = [&](size_t bytes) -> void* {
    void* p = wsb + off;
    off += (bytes + 255) & ~(size_t)255;
    return p;
  };
  short* WoutP = (short*)alloc((size_t)V * KH * 2);
  short* WAe   = (short*)alloc((size_t)NB * 17408 * 2);
  short* WBe   = (short*)alloc((size_t)NB * 34816 * 2);
  short* WAd   = (short*)alloc((size_t)NB * 17408 * 2);
  short* WBd   = (short*)alloc((size_t)NB * 34816 * 2);
  short* WihPe = (short*)alloc((size_t)GP * KE * 2);
  short* WihPd = (short*)alloc((size_t)GP * KE * 2);
  float* b0e   = (float*)alloc(GP * 4);
  float* b1e   = (float*)alloc(GP * 4);
  float* b0d   = (float*)alloc(GP * 4);
  float* b1d   = (float*)alloc(GP * 4);
  short* X0e   = (short*)alloc((size_t)SEQ * GP * SB * 2);   // bf16
  short* X0d   = (short*)alloc((size_t)SEQ * GP * SB * 2);   // bf16
  char*  hst   = (char*)alloc(278528);                       // tagged exchange
  short* H1P   = (short*)alloc((size_t)MROW * KH * 2);
  float* parts = (float*)alloc((size_t)MROW * NBN * 4);

  hipMemsetAsync(d_out, 0, sizeof(float), stream);
  hipMemsetAsync(hst, 0, 278528, stream);

  k_pack_bias<<<(GP + 255) / 256, 256, 0, stream>>>(ebih0, ebhh0, ebih1, ebhh1,
                                                    dbih0, dbhh0, dbih1, dbhh1,
                                                    b0e, b1e, b0d, b1d);
  k_pack_wih<<<(GP * KE / 8 + 255) / 256, 256, 0, stream>>>(eWih0, WihPe);
  k_pack_wih<<<(GP * KE / 8 + 255) / 256, 256, 0, stream>>>(dWih0, WihPd);
  {
    int totA = NB * 2 * 17 * 64, totB = NB * 2 * 34 * 64;
    k_pack_gates<<<(totA + 255) / 256, 256, 0, stream>>>(eWhh0, eWhh0, WAe, 17);
    k_pack_gates<<<(totB + 255) / 256, 256, 0, stream>>>(eWih1, eWhh1, WBe, 34);
    k_pack_gates<<<(totA + 255) / 256, 256, 0, stream>>>(dWhh0, dWhh0, WAd, 17);
    k_pack_gates<<<(totB + 255) / 256, 256, 0, stream>>>(dWih1, dWhh1, WBd, 34);
  }
  k_pack_wout<<<(V * (KH / 8) + 255) / 256, 256, 0, stream>>>(Wout, WoutP);

  k_embproj<<<dim3(GP / 16, 32), 256, 0, stream>>>(WihPe, encemb, x, b0e, X0e);
  k_embproj<<<dim3(GP / 16, 32), 256, 0, stream>>>(WihPd, decemb, y, b0d, X0d);

  RecArgs ra{WAe, WBe, WAd, WBd, X0e, X0d, b1e, b1d, hst, H1P};
  void* kargs[] = {&ra};
  hipLaunchCooperativeKernel((const void*)k_recur, dim3(NB), dim3(256), kargs, 0, stream);

  k_project<<<dim3(MROW / 128, NBN), 256, 0, stream>>>(H1P, WoutP, bout, parts);
  k_finish<<<MROW / 4, 256, 0, stream>>>(parts, H1P, Wout, bout, y, out);
}